// Round 12
// baseline (181.875 us; speedup 1.0000x reference)
//
#include <hip/hip_runtime.h>

#define NN 100000
#define NE 1600000
#define DD 128
#define NBLK 98    // ceil(NN / 1024) (fallback scan)
#define NBUK 782   // ceil(NN / 128) buckets of 128 nodes
#define NB_AC 256  // blocks in hist/scatter passes
#define CHUNK 6250 // NE / NB_AC exactly
#define SCAN_N (NBUK * NB_AC)  // 200192
#define NB_SCAN 196            // ceil(SCAN_N / 1024)

typedef __attribute__((ext_vector_type(8))) short bf16x8;
typedef __attribute__((ext_vector_type(4))) float f32x4;
typedef __attribute__((ext_vector_type(2))) float f32x2;

__device__ __forceinline__ float bf2f(unsigned short u) {
    return __uint_as_float(((unsigned)u) << 16);
}
__device__ __forceinline__ unsigned short f2bf(float f) {
    unsigned u = __float_as_uint(f);
    u += 0x7FFFu + ((u >> 16) & 1u);  // round to nearest even
    return (unsigned short)(u >> 16);
}

// ---------------- A: per-block bucket histogram (LDS atomics only) ----------
__global__ __launch_bounds__(256) void k_hist(const int* __restrict__ col,
                                              unsigned* __restrict__ part) {
    __shared__ unsigned hist[NBUK];
    int t = threadIdx.x, blk = blockIdx.x;
    for (int i = t; i < NBUK; i += 256) hist[i] = 0;
    __syncthreads();
    int beg = blk * CHUNK, end = beg + CHUNK;
    for (int e = beg + t; e < end; e += 256)
        atomicAdd(&hist[col[e] >> 7], 1u);
    __syncthreads();
    for (int i = t; i < NBUK; i += 256)
        part[(size_t)i * NB_AC + blk] = hist[i];  // bucket-major layout
}

// ---------------- B1: block sums of part (scan order) ----------------
__global__ __launch_bounds__(1024) void k_bsum(const unsigned* __restrict__ part,
                                               unsigned* __restrict__ sb) {
    __shared__ unsigned red[1024];
    int t = threadIdx.x;
    int i = blockIdx.x * 1024 + t;
    red[t] = i < SCAN_N ? part[i] : 0;
    __syncthreads();
    for (int off = 512; off > 0; off >>= 1) {
        if (t < off) red[t] += red[t + off];
        __syncthreads();
    }
    if (t == 0) sb[blockIdx.x] = red[0];
}

// ---------------- B2: exclusive scan part -> off ----------------
__global__ __launch_bounds__(1024) void k_scanpart(const unsigned* __restrict__ part,
                                                   const unsigned* __restrict__ sb,
                                                   unsigned* __restrict__ off) {
    __shared__ unsigned s2[256];
    __shared__ unsigned s[1024];
    int t = threadIdx.x;
    if (t < 256) s2[t] = (t < NB_SCAN) ? sb[t] : 0;
    __syncthreads();
    for (int o = 1; o < 256; o <<= 1) {
        unsigned v = 0;
        if (t < 256 && t >= o) v = s2[t - o];
        __syncthreads();
        if (t < 256) s2[t] += v;
        __syncthreads();
    }
    unsigned boff = blockIdx.x == 0 ? 0 : s2[blockIdx.x - 1];
    int i = blockIdx.x * 1024 + t;
    unsigned v = i < SCAN_N ? part[i] : 0;
    s[t] = v;
    __syncthreads();
    for (int o = 1; o < 1024; o <<= 1) {
        unsigned u = t >= o ? s[t - o] : 0;
        __syncthreads();
        s[t] += u;
        __syncthreads();
    }
    if (i < SCAN_N) off[i] = boff + s[t] - v;  // exclusive prefix
}

// ---------------- C: scatter packed edges into bucket-contiguous array -------
__global__ __launch_bounds__(256) void k_scatter_pk(const int* __restrict__ row,
                                                    const int* __restrict__ col,
                                                    const unsigned* __restrict__ off,
                                                    unsigned* __restrict__ packed) {
    __shared__ unsigned cur[NBUK];
    int t = threadIdx.x, blk = blockIdx.x;
    for (int i = t; i < NBUK; i += 256) cur[i] = off[(size_t)i * NB_AC + blk];
    __syncthreads();
    int beg = blk * CHUNK, end = beg + CHUNK;
    for (int e = beg + t; e < end; e += 256) {
        int c = col[e];
        unsigned pos = atomicAdd(&cur[c >> 7], 1u);  // LDS cursor
        packed[pos] = ((unsigned)(c & 127) << 17) | (unsigned)row[e];
    }
}

// ---------------- D: per-bucket CSR finalize: deg/dinv/rowptr/esrc ----------
__global__ __launch_bounds__(256) void k_bucket_csr(const unsigned* __restrict__ off,
                                                    const unsigned* __restrict__ packed,
                                                    float* __restrict__ dinv,
                                                    int* __restrict__ rowptr,
                                                    int* __restrict__ esrc) {
    __shared__ unsigned deg[128], pre[128], tmp[128];
    int t = threadIdx.x;
    int buk = blockIdx.x;
    unsigned bstart = off[(size_t)buk * NB_AC];
    unsigned bend = (buk == NBUK - 1) ? (unsigned)NE : off[(size_t)(buk + 1) * NB_AC];
    if (t < 128) deg[t] = 0;
    __syncthreads();
    for (unsigned e = bstart + t; e < bend; e += 256)
        atomicAdd(&deg[packed[e] >> 17], 1u);
    __syncthreads();
    if (t < 128) tmp[t] = deg[t];
    __syncthreads();
    for (int o = 1; o < 128; o <<= 1) {
        unsigned v = 0;
        if (t < 128 && t >= o) v = tmp[t - o];
        __syncthreads();
        if (t < 128) tmp[t] += v;
        __syncthreads();
    }
    if (t < 128) {
        pre[t] = tmp[t] - deg[t];  // exclusive
        int n = buk * 128 + t;
        if (n < NN) {
            dinv[n] = 1.0f / sqrtf((float)(deg[t] + 1));
            rowptr[n] = (int)(bstart + pre[t]);
        }
    }
    if (buk == NBUK - 1 && t == 0) rowptr[NN] = NE;
    __syncthreads();
    if (t < 128) deg[t] = pre[t];  // reuse as cursor
    __syncthreads();
    for (unsigned e = bstart + t; e < bend; e += 256) {
        unsigned p = packed[e];
        unsigned pos = atomicAdd(&deg[p >> 17], 1u);
        esrc[bstart + pos] = (int)(p & 0x1FFFFu);
    }
}

// ---------------- W -> pre-swizzled bf16 (global, 32 KB) ----------------
__global__ void k_wb(const float* __restrict__ W, unsigned short* __restrict__ wbs) {
    int unit = blockIdx.x * 256 + threadIdx.x;  // 2048 units x 8 elems
    int row = unit >> 4;                        // output-feature row
    int c0 = (unit & 15) * 8;                   // k offset
    float4 v0 = *(const float4*)(W + row * DD + c0);
    float4 v1 = *(const float4*)(W + row * DD + c0 + 4);
    bf16x8 h;
    h[0] = (short)f2bf(v0.x); h[1] = (short)f2bf(v0.y);
    h[2] = (short)f2bf(v0.z); h[3] = (short)f2bf(v0.w);
    h[4] = (short)f2bf(v1.x); h[5] = (short)f2bf(v1.y);
    h[6] = (short)f2bf(v1.z); h[7] = (short)f2bf(v1.w);
    int byte = (row * 256 + c0 * 2) ^ ((row & 7) << 4);  // XOR-swizzle
    *(bf16x8*)((char*)wbs + byte) = h;
}

// ---------------- MFMA GEMM -> fp8 PLANES ----------------
// Plane q (NN x 32 B) holds features n in [32q, 32q+32):
// byte b of plane-q row m = feature n = (2q + (b&1))*16 + (b>>1).
// Lane (lrow,kg) stores ushort {fp8(acc[2q]), fp8(acc[2q+1])} at offset lrow*2.
__global__ __launch_bounds__(256) void k_ygemm(const float* __restrict__ x,
                                               const unsigned short* __restrict__ wbs,
                                               const float* __restrict__ dinv,
                                               unsigned char* __restrict__ yb8) {
    __shared__ unsigned short wb[DD * DD];  // 32 KB, already swizzled
    int t = threadIdx.x;
#pragma unroll
    for (int i = 0; i < 8; ++i)
        ((float4*)wb)[t + 256 * i] = ((const float4*)wbs)[t + 256 * i];
    __syncthreads();

    int wave = t >> 6;
    int lane = t & 63;
    int lrow = lane & 15;   // A row within 16-tile / D col (feature n low part)
    int kg = lane >> 4;     // k-group 0..3

    int arow = blockIdx.x * 64 + wave * 16 + lrow;
    int arc = arow < NN ? arow : NN - 1;  // clamped rows' outputs never written
    bf16x8 afrag[4];
#pragma unroll
    for (int ks = 0; ks < 4; ++ks) {
        const float* src = x + (size_t)arc * DD + ks * 32 + kg * 8;
        float4 v0 = *(const float4*)src;
        float4 v1 = *(const float4*)(src + 4);
        bf16x8 h;
        h[0] = (short)f2bf(v0.x); h[1] = (short)f2bf(v0.y);
        h[2] = (short)f2bf(v0.z); h[3] = (short)f2bf(v0.w);
        h[4] = (short)f2bf(v1.x); h[5] = (short)f2bf(v1.y);
        h[6] = (short)f2bf(v1.z); h[7] = (short)f2bf(v1.w);
        afrag[ks] = h;
    }

    f32x4 acc[8];
#pragma unroll
    for (int ct = 0; ct < 8; ++ct) acc[ct] = (f32x4)(0.f);

#pragma unroll
    for (int ct = 0; ct < 8; ++ct) {
        int wrow = ct * 16 + lrow;  // output-feature index
#pragma unroll
        for (int ks = 0; ks < 4; ++ks) {
            int byte = (wrow * 256 + ks * 64 + kg * 16) ^ ((wrow & 7) << 4);
            bf16x8 bfrag = *(const bf16x8*)((char*)wb + byte);
            acc[ct] = __builtin_amdgcn_mfma_f32_16x16x32_bf16(afrag[ks], bfrag, acc[ct], 0, 0, 0);
        }
    }

    // epilogue: per row m, per plane q, store ushort {fp8(n=32q+lrow), fp8(n=32q+16+lrow)}
#pragma unroll
    for (int j = 0; j < 4; ++j) {
        int m = blockIdx.x * 64 + wave * 16 + kg * 4 + j;
        if (m < NN) {
            float s = dinv[m];
#pragma unroll
            for (int q = 0; q < 4; ++q) {
                unsigned w = __builtin_amdgcn_cvt_pk_fp8_f32(s * acc[2 * q][j],
                                                             s * acc[2 * q + 1][j], 0, false);
                *(unsigned short*)(yb8 + ((size_t)q * NN + m) * 32 + lrow * 2) =
                    (unsigned short)w;
            }
        }
    }
}

// ---------------- pass-gather over one 32-feature plane ----------------
// 32 lanes/node = 4 edge-subsets x 8 feature-dwords. Plane is 3.2 MB -> L2-resident.
// lane dword d covers n-offsets {2d (lo.x), 2d+1 (hi.x), 16+2d (lo.y), 16+2d+1 (hi.y)}.
__global__ __launch_bounds__(256) void k_gpass(const int* __restrict__ rowptr,
                                               const int* __restrict__ esrc,
                                               const unsigned char* __restrict__ plane,
                                               const float* __restrict__ xq,
                                               const float* __restrict__ dinv,
                                               const float* __restrict__ biasq,
                                               float* __restrict__ outq) {
    int t = threadIdx.x;
    int node = blockIdx.x * 8 + (t >> 5);
    if (node >= NN) return;
    int l = t & 31;
    int sub = l >> 3;   // edge subset 0..3
    int d = l & 7;      // feature dword 0..7
    int beg = rowptr[node];
    int end = rowptr[node + 1];

    f32x2 lo = (f32x2)(0.f), hi = (f32x2)(0.f);
    int e = beg;
    for (; e + 8 <= end; e += 8) {
        int s0 = esrc[e + sub];
        int s1 = esrc[e + 4 + sub];
        unsigned v0 = *(const unsigned*)(plane + (size_t)s0 * 32 + d * 4);
        unsigned v1 = *(const unsigned*)(plane + (size_t)s1 * 32 + d * 4);
        lo += __builtin_amdgcn_cvt_pk_f32_fp8(v0, false);
        hi += __builtin_amdgcn_cvt_pk_f32_fp8(v0, true);
        lo += __builtin_amdgcn_cvt_pk_f32_fp8(v1, false);
        hi += __builtin_amdgcn_cvt_pk_f32_fp8(v1, true);
    }
    for (; e < end; e += 4) {
        int ee = e + sub;
        unsigned v = 0;
        if (ee < end) {
            int s = esrc[ee];
            v = *(const unsigned*)(plane + (size_t)s * 32 + d * 4);
        }
        lo += __builtin_amdgcn_cvt_pk_f32_fp8(v, false);
        hi += __builtin_amdgcn_cvt_pk_f32_fp8(v, true);
    }

    // reduce over the 4 edge-subsets (lanes differing in bits 3..4)
    lo.x += __shfl_xor(lo.x, 8);  lo.x += __shfl_xor(lo.x, 16);
    lo.y += __shfl_xor(lo.y, 8);  lo.y += __shfl_xor(lo.y, 16);
    hi.x += __shfl_xor(hi.x, 8);  hi.x += __shfl_xor(hi.x, 16);
    hi.y += __shfl_xor(hi.y, 8);  hi.y += __shfl_xor(hi.y, 16);

    if (sub == 0) {
        // self-loop term (added once)
        unsigned sv = *(const unsigned*)(plane + (size_t)node * 32 + d * 4);
        lo += __builtin_amdgcn_cvt_pk_f32_fp8(sv, false);
        hi += __builtin_amdgcn_cvt_pk_f32_fp8(sv, true);

        float dc = dinv[node];
        f32x2 ba = *(const f32x2*)(biasq + 2 * d);
        f32x2 bb = *(const f32x2*)(biasq + 16 + 2 * d);
        f32x2 xa = __builtin_nontemporal_load((const f32x2*)(xq + (size_t)node * DD + 2 * d));
        f32x2 xb = __builtin_nontemporal_load((const f32x2*)(xq + (size_t)node * DD + 16 + 2 * d));
        f32x2 oa, ob;
        oa.x = xa.x + fmaxf(dc * lo.x + ba.x, 0.f);
        oa.y = xa.y + fmaxf(dc * hi.x + ba.y, 0.f);
        ob.x = xb.x + fmaxf(dc * lo.y + bb.x, 0.f);
        ob.y = xb.y + fmaxf(dc * hi.y + bb.y, 0.f);
        __builtin_nontemporal_store(oa, (f32x2*)(outq + (size_t)node * DD + 2 * d));
        __builtin_nontemporal_store(ob, (f32x2*)(outq + (size_t)node * DD + 16 + 2 * d));
    }
}

// ================= fallback path (small ws) =================
__global__ void k_count(const int* __restrict__ col, int* __restrict__ deg) {
    int i = blockIdx.x * blockDim.x + threadIdx.x;
    if (i < NE) atomicAdd(&deg[col[i]], 1);
}
__global__ __launch_bounds__(1024) void k_blocksum_dinv(const int* __restrict__ deg,
                                                        int* __restrict__ bsum,
                                                        float* __restrict__ dinv) {
    __shared__ int red[1024];
    int t = threadIdx.x;
    int i = blockIdx.x * 1024 + t;
    int d = i < NN ? deg[i] : 0;
    if (i < NN) dinv[i] = 1.0f / sqrtf((float)(d + 1));
    red[t] = d;
    __syncthreads();
    for (int off = 512; off > 0; off >>= 1) {
        if (t < off) red[t] += red[t + off];
        __syncthreads();
    }
    if (t == 0) bsum[blockIdx.x] = red[0];
}
__global__ void k_scanbsum(const int* __restrict__ bsum, int* __restrict__ boff) {
    __shared__ int s[128];
    int t = threadIdx.x;
    s[t] = t < NBLK ? bsum[t] : 0;
    __syncthreads();
    for (int off = 1; off < 128; off <<= 1) {
        int v = t >= off ? s[t - off] : 0;
        __syncthreads();
        s[t] += v;
        __syncthreads();
    }
    if (t < NBLK) boff[t] = (t == 0) ? 0 : s[t - 1];
}
__global__ __launch_bounds__(1024) void k_scanwrite(const int* __restrict__ deg,
                                                    const int* __restrict__ boff,
                                                    int* __restrict__ rowptr) {
    __shared__ int s[1024];
    int t = threadIdx.x;
    int i = blockIdx.x * 1024 + t;
    int v = i < NN ? deg[i] : 0;
    s[t] = v;
    __syncthreads();
    for (int off = 1; off < 1024; off <<= 1) {
        int u = t >= off ? s[t - off] : 0;
        __syncthreads();
        s[t] += u;
        __syncthreads();
    }
    if (i < NN) rowptr[i] = boff[blockIdx.x] + s[t] - v;
    if (i == 0) rowptr[NN] = NE;
}
__global__ void k_fill(const int* __restrict__ row, const int* __restrict__ col,
                       const int* __restrict__ rowptr, int* __restrict__ cnt,
                       int* __restrict__ esrc) {
    int i = blockIdx.x * blockDim.x + threadIdx.x;
    if (i < NE) {
        int c = col[i];
        int pos = rowptr[c] + atomicAdd(&cnt[c], 1);
        esrc[pos] = row[i];
    }
}
__global__ __launch_bounds__(256) void k_gather(const int* __restrict__ rowptr,
                                                const int* __restrict__ esrc,
                                                const float* __restrict__ x,
                                                const float* __restrict__ dinv,
                                                float* __restrict__ agg) {
    int t = threadIdx.x;
    int lane = t & 31;
    int node = blockIdx.x * 8 + (t >> 5);
    if (node >= NN) return;
    int beg = rowptr[node];
    int end = rowptr[node + 1];
    float dc = dinv[node];
    float4 xv = ((const float4*)(x + (size_t)node * DD))[lane];
    float4 acc;
    acc.x = dc * xv.x; acc.y = dc * xv.y; acc.z = dc * xv.z; acc.w = dc * xv.w;
    int e = beg;
    for (; e + 1 < end; e += 2) {
        int r0 = esrc[e];
        int r1 = esrc[e + 1];
        float s0 = dinv[r0];
        float s1 = dinv[r1];
        float4 v0 = ((const float4*)(x + (size_t)r0 * DD))[lane];
        float4 v1 = ((const float4*)(x + (size_t)r1 * DD))[lane];
        acc.x += s0 * v0.x + s1 * v1.x;
        acc.y += s0 * v0.y + s1 * v1.y;
        acc.z += s0 * v0.z + s1 * v1.z;
        acc.w += s0 * v0.w + s1 * v1.w;
    }
    if (e < end) {
        int r = esrc[e];
        float s = dinv[r];
        float4 v = ((const float4*)(x + (size_t)r * DD))[lane];
        acc.x += s * v.x; acc.y += s * v.y; acc.z += s * v.z; acc.w += s * v.w;
    }
    acc.x *= dc; acc.y *= dc; acc.z *= dc; acc.w *= dc;
    ((float4*)(agg + (size_t)node * DD))[lane] = acc;
}
__global__ void k_transpose_w(const float* __restrict__ W, float* __restrict__ Wt) {
    int c = blockIdx.x;
    int k = threadIdx.x;
    Wt[k * DD + c] = W[c * DD + k];
}
__global__ __launch_bounds__(256) void k_gemm(const float* __restrict__ x,
                                              const float* __restrict__ Wt,
                                              const float* __restrict__ bias,
                                              float* __restrict__ out) {
    __shared__ float wt[DD * DD];
    int t = threadIdx.x;
    for (int i = t; i < DD * DD / 4; i += 256)
        ((float4*)wt)[i] = ((const float4*)Wt)[i];
    __syncthreads();

    int grp = t >> 5;
    int c4  = (t & 31) * 4;
    int rbase = blockIdx.x * 64 + grp * 8;

    float acc[8][4];
#pragma unroll
    for (int i = 0; i < 8; i++)
#pragma unroll
        for (int j = 0; j < 4; j++) acc[i][j] = 0.0f;

    for (int k = 0; k < DD; k += 4) {
        float4 w0 = *(const float4*)&wt[(k + 0) * DD + c4];
        float4 w1 = *(const float4*)&wt[(k + 1) * DD + c4];
        float4 w2 = *(const float4*)&wt[(k + 2) * DD + c4];
        float4 w3 = *(const float4*)&wt[(k + 3) * DD + c4];
#pragma unroll
        for (int i = 0; i < 8; i++) {
            int rr = rbase + i;
            rr = rr < NN ? rr : NN - 1;
            float4 a = *(const float4*)&out[(size_t)rr * DD + k];
            acc[i][0] += a.x * w0.x + a.y * w1.x + a.z * w2.x + a.w * w3.x;
            acc[i][1] += a.x * w0.y + a.y * w1.y + a.z * w2.y + a.w * w3.y;
            acc[i][2] += a.x * w0.z + a.y * w1.z + a.z * w2.z + a.w * w3.z;
            acc[i][3] += a.x * w0.w + a.y * w1.w + a.z * w2.w + a.w * w3.w;
        }
    }

    float4 bv = *(const float4*)&bias[c4];
#pragma unroll
    for (int i = 0; i < 8; i++) {
        int r = rbase + i;
        if (r < NN) {
            float4 xv = *(const float4*)&x[(size_t)r * DD + c4];
            float4 o;
            o.x = xv.x + fmaxf(acc[i][0] + bv.x, 0.0f);
            o.y = xv.y + fmaxf(acc[i][1] + bv.y, 0.0f);
            o.z = xv.z + fmaxf(acc[i][2] + bv.z, 0.0f);
            o.w = xv.w + fmaxf(acc[i][3] + bv.w, 0.0f);
            *(float4*)&out[(size_t)r * DD + c4] = o;
        }
    }
}

extern "C" void kernel_launch(void* const* d_in, const int* in_sizes, int n_in,
                              void* d_out, int out_size, void* d_ws, size_t ws_size,
                              hipStream_t stream) {
    const float* x   = (const float*)d_in[0];
    const int*   ei  = (const int*)d_in[1];
    const float* W   = (const float*)d_in[2];
    const float* b   = (const float*)d_in[3];
    const int* row = ei;        // edge_index[0] = source
    const int* col = ei + NE;   // edge_index[1] = target

    float* out = (float*)d_out;

    // workspace layout (bytes), 16-B aligned:
    //   part   : [0,         800768)   u32[SCAN_N]
    //   off    : [800768,   1601536)   u32[SCAN_N]
    //   sb     : [1601536,  1602352)   u32[196] (+pad)
    //   dinv   : [1602352,  2002352)
    //   rowptr : [2002352,  2402356) -> region to 2402368
    //   packed : [2402368,  8802368)   u32[NE]
    //   wbs    : [8802368,  8867904)
    //   esrc   : [8867904, 15267904)
    //   yb8    : [15267904, 28067904)  4 planes x NN x 32 B
    char* ws = (char*)d_ws;
    unsigned* part   = (unsigned*)ws;
    unsigned* off    = (unsigned*)(ws + 800768);
    unsigned* sb     = (unsigned*)(ws + 1601536);
    float*    dinv   = (float*)(ws + 1602352);
    int*      rowptr = (int*)(ws + 2002352);
    unsigned* packed = (unsigned*)(ws + 2402368);
    unsigned short* wbs = (unsigned short*)(ws + 8802368);
    float*    Wt     = (float*)(ws + 8802368);
    int*      esrc   = (int*)(ws + 8867904);
    unsigned char* yb8 = (unsigned char*)(ws + 15267904);

    bool big_ws = ws_size >= 28100000;

    if (big_ws) {
        k_hist<<<NB_AC, 256, 0, stream>>>(col, part);
        k_bsum<<<NB_SCAN, 1024, 0, stream>>>(part, sb);
        k_scanpart<<<NB_SCAN, 1024, 0, stream>>>(part, sb, off);
        k_scatter_pk<<<NB_AC, 256, 0, stream>>>(row, col, off, packed);
        k_bucket_csr<<<NBUK, 256, 0, stream>>>(off, packed, dinv, rowptr, esrc);
        k_wb<<<8, 256, 0, stream>>>(W, wbs);
        k_ygemm<<<(NN + 63) / 64, 256, 0, stream>>>(x, wbs, dinv, yb8);
        for (int q = 0; q < 4; ++q) {
            k_gpass<<<(NN + 7) / 8, 256, 0, stream>>>(
                rowptr, esrc, yb8 + (size_t)q * NN * 32,
                x + q * 32, dinv, b + q * 32, out + q * 32);
        }
    } else {
        int* cnt  = (int*)ws;                 // reuse part region
        int* bsum = (int*)(ws + 1601536);     // 98 ints fit in sb region
        int* boff = (int*)(ws + 400000);      // inside part region, after cnt
        hipMemsetAsync(cnt, 0, NN * sizeof(int), stream);
        k_count<<<(NE + 255) / 256, 256, 0, stream>>>(col, cnt);
        k_blocksum_dinv<<<NBLK, 1024, 0, stream>>>(cnt, bsum, dinv);
        k_scanbsum<<<1, 128, 0, stream>>>(bsum, boff);
        k_scanwrite<<<NBLK, 1024, 0, stream>>>(cnt, boff, rowptr);
        hipMemsetAsync(cnt, 0, NN * sizeof(int), stream);
        k_fill<<<(NE + 255) / 256, 256, 0, stream>>>(row, col, rowptr, cnt, esrc);
        k_gather<<<(NN + 7) / 8, 256, 0, stream>>>(rowptr, esrc, x, dinv, out);
        k_transpose_w<<<DD, DD, 0, stream>>>(W, Wt);
        k_gemm<<<(NN + 63) / 64, 256, 0, stream>>>(x, Wt, b, out);
    }
}

// Round 13
// 145.608 us; speedup vs baseline: 1.2491x; 1.2491x over previous
//
#include <hip/hip_runtime.h>

#define NN 100000
#define NE 1600000
#define DD 128
#define NBLK 98    // ceil(NN / 1024) (fallback scan)
#define NBUK 782   // ceil(NN / 128) buckets of 128 nodes
#define NB_AC 1000 // blocks in hist/scatter passes
#define CHUNK 1600 // NE / NB_AC exactly
#define SCAN_N (NBUK * NB_AC)  // 782000
#define NB_SCAN 764            // ceil(SCAN_N / 1024)

typedef __attribute__((ext_vector_type(8))) short bf16x8;
typedef __attribute__((ext_vector_type(4))) float f32x4;
typedef __attribute__((ext_vector_type(2))) float f32x2;

__device__ __forceinline__ float bf2f(unsigned short u) {
    return __uint_as_float(((unsigned)u) << 16);
}
__device__ __forceinline__ unsigned short f2bf(float f) {
    unsigned u = __float_as_uint(f);
    u += 0x7FFFu + ((u >> 16) & 1u);  // round to nearest even
    return (unsigned short)(u >> 16);
}

// ---------------- A: per-block bucket histogram (LDS atomics only) ----------
__global__ __launch_bounds__(256) void k_hist(const int* __restrict__ col,
                                              unsigned* __restrict__ part) {
    __shared__ unsigned hist[NBUK];
    int t = threadIdx.x, blk = blockIdx.x;
    for (int i = t; i < NBUK; i += 256) hist[i] = 0;
    __syncthreads();
    int beg = blk * CHUNK, end = beg + CHUNK;
    for (int e = beg + t; e < end; e += 256)
        atomicAdd(&hist[col[e] >> 7], 1u);
    __syncthreads();
    for (int i = t; i < NBUK; i += 256)
        part[(size_t)i * NB_AC + blk] = hist[i];  // bucket-major layout
}

// ---------------- B1: block sums of part (scan order) ----------------
__global__ __launch_bounds__(1024) void k_bsum(const unsigned* __restrict__ part,
                                               unsigned* __restrict__ sb) {
    __shared__ unsigned red[1024];
    int t = threadIdx.x;
    int i = blockIdx.x * 1024 + t;
    red[t] = i < SCAN_N ? part[i] : 0;
    __syncthreads();
    for (int off = 512; off > 0; off >>= 1) {
        if (t < off) red[t] += red[t + off];
        __syncthreads();
    }
    if (t == 0) sb[blockIdx.x] = red[0];
}

// ---------------- B2: exclusive scan part -> off (redundant sb scan/block) ----
__global__ __launch_bounds__(1024) void k_scanpart(const unsigned* __restrict__ part,
                                                   const unsigned* __restrict__ sb,
                                                   unsigned* __restrict__ off) {
    __shared__ unsigned s2[1024];
    __shared__ unsigned s[1024];
    int t = threadIdx.x;
    s2[t] = (t < NB_SCAN) ? sb[t] : 0;
    __syncthreads();
    for (int o = 1; o < 1024; o <<= 1) {
        unsigned v = t >= o ? s2[t - o] : 0;
        __syncthreads();
        s2[t] += v;
        __syncthreads();
    }
    unsigned boff = blockIdx.x == 0 ? 0 : s2[blockIdx.x - 1];
    int i = blockIdx.x * 1024 + t;
    unsigned v = i < SCAN_N ? part[i] : 0;
    s[t] = v;
    __syncthreads();
    for (int o = 1; o < 1024; o <<= 1) {
        unsigned u = t >= o ? s[t - o] : 0;
        __syncthreads();
        s[t] += u;
        __syncthreads();
    }
    if (i < SCAN_N) off[i] = boff + s[t] - v;  // exclusive prefix
}

// ---------------- C: scatter packed edges into bucket-contiguous array -------
__global__ __launch_bounds__(256) void k_scatter_pk(const int* __restrict__ row,
                                                    const int* __restrict__ col,
                                                    const unsigned* __restrict__ off,
                                                    unsigned* __restrict__ packed) {
    __shared__ unsigned cur[NBUK];
    int t = threadIdx.x, blk = blockIdx.x;
    for (int i = t; i < NBUK; i += 256) cur[i] = off[(size_t)i * NB_AC + blk];
    __syncthreads();
    int beg = blk * CHUNK, end = beg + CHUNK;
    for (int e = beg + t; e < end; e += 256) {
        int c = col[e];
        unsigned pos = atomicAdd(&cur[c >> 7], 1u);  // LDS cursor
        packed[pos] = ((unsigned)(c & 127) << 17) | (unsigned)row[e];
    }
}

// ---------------- D: per-bucket CSR finalize: deg/dinv/rowptr/esrc ----------
__global__ __launch_bounds__(256) void k_bucket_csr(const unsigned* __restrict__ off,
                                                    const unsigned* __restrict__ packed,
                                                    float* __restrict__ dinv,
                                                    int* __restrict__ rowptr,
                                                    int* __restrict__ esrc) {
    __shared__ unsigned deg[128], pre[128], tmp[128];
    int t = threadIdx.x;
    int buk = blockIdx.x;
    unsigned bstart = off[(size_t)buk * NB_AC];
    unsigned bend = (buk == NBUK - 1) ? (unsigned)NE : off[(size_t)(buk + 1) * NB_AC];
    if (t < 128) deg[t] = 0;
    __syncthreads();
    for (unsigned e = bstart + t; e < bend; e += 256)
        atomicAdd(&deg[packed[e] >> 17], 1u);
    __syncthreads();
    if (t < 128) tmp[t] = deg[t];
    __syncthreads();
    for (int o = 1; o < 128; o <<= 1) {
        unsigned v = 0;
        if (t < 128 && t >= o) v = tmp[t - o];
        __syncthreads();
        if (t < 128) tmp[t] += v;
        __syncthreads();
    }
    if (t < 128) {
        pre[t] = tmp[t] - deg[t];  // exclusive
        int n = buk * 128 + t;
        if (n < NN) {
            dinv[n] = 1.0f / sqrtf((float)(deg[t] + 1));
            rowptr[n] = (int)(bstart + pre[t]);
        }
    }
    if (buk == NBUK - 1 && t == 0) rowptr[NN] = NE;
    __syncthreads();
    if (t < 128) deg[t] = pre[t];  // reuse as cursor
    __syncthreads();
    for (unsigned e = bstart + t; e < bend; e += 256) {
        unsigned p = packed[e];
        unsigned pos = atomicAdd(&deg[p >> 17], 1u);
        esrc[bstart + pos] = (int)(p & 0x1FFFFu);
    }
}

// ---------------- W -> pre-swizzled bf16 (global, 32 KB) ----------------
__global__ void k_wb(const float* __restrict__ W, unsigned short* __restrict__ wbs) {
    int unit = blockIdx.x * 256 + threadIdx.x;  // 2048 units x 8 elems
    int row = unit >> 4;                        // output-feature row
    int c0 = (unit & 15) * 8;                   // k offset
    float4 v0 = *(const float4*)(W + row * DD + c0);
    float4 v1 = *(const float4*)(W + row * DD + c0 + 4);
    bf16x8 h;
    h[0] = (short)f2bf(v0.x); h[1] = (short)f2bf(v0.y);
    h[2] = (short)f2bf(v0.z); h[3] = (short)f2bf(v0.w);
    h[4] = (short)f2bf(v1.x); h[5] = (short)f2bf(v1.y);
    h[6] = (short)f2bf(v1.z); h[7] = (short)f2bf(v1.w);
    int byte = (row * 256 + c0 * 2) ^ ((row & 7) << 4);  // XOR-swizzle
    *(bf16x8*)((char*)wbs + byte) = h;
}

// ---------------- MFMA GEMM: yb8[m] = fp8( dinv[m] * (x[m] @ W^T) ), permuted ----
// Byte p of row m holds feature n = (p&7)*16 + (p>>3)  (writer-natural order).
__global__ __launch_bounds__(256) void k_ygemm(const float* __restrict__ x,
                                               const unsigned short* __restrict__ wbs,
                                               const float* __restrict__ dinv,
                                               unsigned char* __restrict__ yb8) {
    __shared__ unsigned short wb[DD * DD];  // 32 KB, already swizzled
    int t = threadIdx.x;
#pragma unroll
    for (int i = 0; i < 8; ++i)
        ((float4*)wb)[t + 256 * i] = ((const float4*)wbs)[t + 256 * i];
    __syncthreads();

    int wave = t >> 6;
    int lane = t & 63;
    int lrow = lane & 15;   // A row within 16-tile / D col (feature n)
    int kg = lane >> 4;     // k-group 0..3

    int arow = blockIdx.x * 64 + wave * 16 + lrow;
    int arc = arow < NN ? arow : NN - 1;  // clamped rows' outputs never written
    bf16x8 afrag[4];
#pragma unroll
    for (int ks = 0; ks < 4; ++ks) {
        const float* src = x + (size_t)arc * DD + ks * 32 + kg * 8;
        float4 v0 = *(const float4*)src;
        float4 v1 = *(const float4*)(src + 4);
        bf16x8 h;
        h[0] = (short)f2bf(v0.x); h[1] = (short)f2bf(v0.y);
        h[2] = (short)f2bf(v0.z); h[3] = (short)f2bf(v0.w);
        h[4] = (short)f2bf(v1.x); h[5] = (short)f2bf(v1.y);
        h[6] = (short)f2bf(v1.z); h[7] = (short)f2bf(v1.w);
        afrag[ks] = h;
    }

    f32x4 acc[8];
#pragma unroll
    for (int ct = 0; ct < 8; ++ct) acc[ct] = (f32x4)(0.f);

#pragma unroll
    for (int ct = 0; ct < 8; ++ct) {
        int wrow = ct * 16 + lrow;  // output-feature index
#pragma unroll
        for (int ks = 0; ks < 4; ++ks) {
            int byte = (wrow * 256 + ks * 64 + kg * 16) ^ ((wrow & 7) << 4);
            bf16x8 bfrag = *(const bf16x8*)((char*)wb + byte);
            acc[ct] = __builtin_amdgcn_mfma_f32_16x16x32_bf16(afrag[ks], bfrag, acc[ct], 0, 0, 0);
        }
    }

    // epilogue: pack the 8 ct-values as 8 consecutive fp8 bytes at offset lrow*8.
#pragma unroll
    for (int j = 0; j < 4; ++j) {
        int m = blockIdx.x * 64 + wave * 16 + kg * 4 + j;
        if (m < NN) {
            float s = dinv[m];
            unsigned w0 = 0, w1 = 0;
            w0 = __builtin_amdgcn_cvt_pk_fp8_f32(s * acc[0][j], s * acc[1][j], w0, false);
            w0 = __builtin_amdgcn_cvt_pk_fp8_f32(s * acc[2][j], s * acc[3][j], w0, true);
            w1 = __builtin_amdgcn_cvt_pk_fp8_f32(s * acc[4][j], s * acc[5][j], w1, false);
            w1 = __builtin_amdgcn_cvt_pk_fp8_f32(s * acc[6][j], s * acc[7][j], w1, true);
            uint2 o; o.x = w0; o.y = w1;
            *(uint2*)(yb8 + (size_t)m * DD + lrow * 8) = o;
        }
    }
}

// ---------------- fused gather (fp8) + epilogue (single pass, R9-proven) -----
__global__ __launch_bounds__(256) void k_gather_fp8(const int* __restrict__ rowptr,
                                                    const int* __restrict__ esrc,
                                                    const unsigned char* __restrict__ yb8,
                                                    const float* __restrict__ x,
                                                    const float* __restrict__ dinv,
                                                    const float* __restrict__ bias,
                                                    float* __restrict__ out) {
    int t = threadIdx.x;
    int gl = t & 31;
    int node = blockIdx.x * 8 + (t >> 5);
    if (node >= NN) return;
    int beg = rowptr[node];
    int end = rowptr[node + 1];
    float dc = dinv[node];

    // self term
    unsigned su = *(const unsigned*)(yb8 + (size_t)node * DD + gl * 4);
    f32x2 a01 = __builtin_amdgcn_cvt_pk_f32_fp8(su, false);
    f32x2 a23 = __builtin_amdgcn_cvt_pk_f32_fp8(su, true);

    int e = beg;
    for (; e + 7 < end; e += 8) {
        unsigned uu[8];
#pragma unroll
        for (int u = 0; u < 8; ++u) {
            int r = esrc[e + u];
            uu[u] = *(const unsigned*)(yb8 + (size_t)r * DD + gl * 4);
        }
#pragma unroll
        for (int u = 0; u < 8; ++u) {
            a01 += __builtin_amdgcn_cvt_pk_f32_fp8(uu[u], false);
            a23 += __builtin_amdgcn_cvt_pk_f32_fp8(uu[u], true);
        }
    }
    for (; e < end; ++e) {
        int r = esrc[e];
        unsigned u = *(const unsigned*)(yb8 + (size_t)r * DD + gl * 4);
        a01 += __builtin_amdgcn_cvt_pk_f32_fp8(u, false);
        a23 += __builtin_amdgcn_cvt_pk_f32_fp8(u, true);
    }

    float vals[4] = {a01.x, a01.y, a23.x, a23.y};
    int q = gl >> 1;          // p>>3 for all 4 positions
    int c0 = (gl & 1) * 4;    // (p&7) base
#pragma unroll
    for (int i = 0; i < 4; ++i) {
        int n = (c0 + i) * 16 + q;
        float h = dc * vals[i] + bias[n];
        out[(size_t)node * DD + n] = x[(size_t)node * DD + n] + fmaxf(h, 0.f);
    }
}

// ================= fallback path (small ws) =================
__global__ void k_count(const int* __restrict__ col, int* __restrict__ deg) {
    int i = blockIdx.x * blockDim.x + threadIdx.x;
    if (i < NE) atomicAdd(&deg[col[i]], 1);
}
__global__ __launch_bounds__(1024) void k_blocksum_dinv(const int* __restrict__ deg,
                                                        int* __restrict__ bsum,
                                                        float* __restrict__ dinv) {
    __shared__ int red[1024];
    int t = threadIdx.x;
    int i = blockIdx.x * 1024 + t;
    int d = i < NN ? deg[i] : 0;
    if (i < NN) dinv[i] = 1.0f / sqrtf((float)(d + 1));
    red[t] = d;
    __syncthreads();
    for (int off = 512; off > 0; off >>= 1) {
        if (t < off) red[t] += red[t + off];
        __syncthreads();
    }
    if (t == 0) bsum[blockIdx.x] = red[0];
}
__global__ void k_scanbsum(const int* __restrict__ bsum, int* __restrict__ boff) {
    __shared__ int s[128];
    int t = threadIdx.x;
    s[t] = t < NBLK ? bsum[t] : 0;
    __syncthreads();
    for (int off = 1; off < 128; off <<= 1) {
        int v = t >= off ? s[t - off] : 0;
        __syncthreads();
        s[t] += v;
        __syncthreads();
    }
    if (t < NBLK) boff[t] = (t == 0) ? 0 : s[t - 1];
}
__global__ __launch_bounds__(1024) void k_scanwrite(const int* __restrict__ deg,
                                                    const int* __restrict__ boff,
                                                    int* __restrict__ rowptr) {
    __shared__ int s[1024];
    int t = threadIdx.x;
    int i = blockIdx.x * 1024 + t;
    int v = i < NN ? deg[i] : 0;
    s[t] = v;
    __syncthreads();
    for (int off = 1; off < 1024; off <<= 1) {
        int u = t >= off ? s[t - off] : 0;
        __syncthreads();
        s[t] += u;
        __syncthreads();
    }
    if (i < NN) rowptr[i] = boff[blockIdx.x] + s[t] - v;
    if (i == 0) rowptr[NN] = NE;
}
__global__ void k_fill(const int* __restrict__ row, const int* __restrict__ col,
                       const int* __restrict__ rowptr, int* __restrict__ cnt,
                       int* __restrict__ esrc) {
    int i = blockIdx.x * blockDim.x + threadIdx.x;
    if (i < NE) {
        int c = col[i];
        int pos = rowptr[c] + atomicAdd(&cnt[c], 1);
        esrc[pos] = row[i];
    }
}
__global__ __launch_bounds__(256) void k_gather(const int* __restrict__ rowptr,
                                                const int* __restrict__ esrc,
                                                const float* __restrict__ x,
                                                const float* __restrict__ dinv,
                                                float* __restrict__ agg) {
    int t = threadIdx.x;
    int lane = t & 31;
    int node = blockIdx.x * 8 + (t >> 5);
    if (node >= NN) return;
    int beg = rowptr[node];
    int end = rowptr[node + 1];
    float dc = dinv[node];
    float4 xv = ((const float4*)(x + (size_t)node * DD))[lane];
    float4 acc;
    acc.x = dc * xv.x; acc.y = dc * xv.y; acc.z = dc * xv.z; acc.w = dc * xv.w;
    int e = beg;
    for (; e + 1 < end; e += 2) {
        int r0 = esrc[e];
        int r1 = esrc[e + 1];
        float s0 = dinv[r0];
        float s1 = dinv[r1];
        float4 v0 = ((const float4*)(x + (size_t)r0 * DD))[lane];
        float4 v1 = ((const float4*)(x + (size_t)r1 * DD))[lane];
        acc.x += s0 * v0.x + s1 * v1.x;
        acc.y += s0 * v0.y + s1 * v1.y;
        acc.z += s0 * v0.z + s1 * v1.z;
        acc.w += s0 * v0.w + s1 * v1.w;
    }
    if (e < end) {
        int r = esrc[e];
        float s = dinv[r];
        float4 v = ((const float4*)(x + (size_t)r * DD))[lane];
        acc.x += s * v.x; acc.y += s * v.y; acc.z += s * v.z; acc.w += s * v.w;
    }
    acc.x *= dc; acc.y *= dc; acc.z *= dc; acc.w *= dc;
    ((float4*)(agg + (size_t)node * DD))[lane] = acc;
}
__global__ void k_transpose_w(const float* __restrict__ W, float* __restrict__ Wt) {
    int c = blockIdx.x;
    int k = threadIdx.x;
    Wt[k * DD + c] = W[c * DD + k];
}
__global__ __launch_bounds__(256) void k_gemm(const float* __restrict__ x,
                                              const float* __restrict__ Wt,
                                              const float* __restrict__ bias,
                                              float* __restrict__ out) {
    __shared__ float wt[DD * DD];
    int t = threadIdx.x;
    for (int i = t; i < DD * DD / 4; i += 256)
        ((float4*)wt)[i] = ((const float4*)Wt)[i];
    __syncthreads();

    int grp = t >> 5;
    int c4  = (t & 31) * 4;
    int rbase = blockIdx.x * 64 + grp * 8;

    float acc[8][4];
#pragma unroll
    for (int i = 0; i < 8; i++)
#pragma unroll
        for (int j = 0; j < 4; j++) acc[i][j] = 0.0f;

    for (int k = 0; k < DD; k += 4) {
        float4 w0 = *(const float4*)&wt[(k + 0) * DD + c4];
        float4 w1 = *(const float4*)&wt[(k + 1) * DD + c4];
        float4 w2 = *(const float4*)&wt[(k + 2) * DD + c4];
        float4 w3 = *(const float4*)&wt[(k + 3) * DD + c4];
#pragma unroll
        for (int i = 0; i < 8; i++) {
            int rr = rbase + i;
            rr = rr < NN ? rr : NN - 1;
            float4 a = *(const float4*)&out[(size_t)rr * DD + k];
            acc[i][0] += a.x * w0.x + a.y * w1.x + a.z * w2.x + a.w * w3.x;
            acc[i][1] += a.x * w0.y + a.y * w1.y + a.z * w2.y + a.w * w3.y;
            acc[i][2] += a.x * w0.z + a.y * w1.z + a.z * w2.z + a.w * w3.z;
            acc[i][3] += a.x * w0.w + a.y * w1.w + a.z * w2.w + a.w * w3.w;
        }
    }

    float4 bv = *(const float4*)&bias[c4];
#pragma unroll
    for (int i = 0; i < 8; i++) {
        int r = rbase + i;
        if (r < NN) {
            float4 xv = *(const float4*)&x[(size_t)r * DD + c4];
            float4 o;
            o.x = xv.x + fmaxf(acc[i][0] + bv.x, 0.0f);
            o.y = xv.y + fmaxf(acc[i][1] + bv.y, 0.0f);
            o.z = xv.z + fmaxf(acc[i][2] + bv.z, 0.0f);
            o.w = xv.w + fmaxf(acc[i][3] + bv.w, 0.0f);
            *(float4*)&out[(size_t)r * DD + c4] = o;
        }
    }
}

extern "C" void kernel_launch(void* const* d_in, const int* in_sizes, int n_in,
                              void* d_out, int out_size, void* d_ws, size_t ws_size,
                              hipStream_t stream) {
    const float* x   = (const float*)d_in[0];
    const int*   ei  = (const int*)d_in[1];
    const float* W   = (const float*)d_in[2];
    const float* b   = (const float*)d_in[3];
    const int* row = ei;        // edge_index[0] = source
    const int* col = ei + NE;   // edge_index[1] = target

    float* out = (float*)d_out;

    // workspace layout (bytes), 16-B aligned:
    //   part   : [0,         3128000)   u32[SCAN_N]
    //   off    : [3128000,   6256000)   u32[SCAN_N]
    //   sb     : [6256000,   6259072)   u32[764] (+pad)
    //   dinv   : [6259072,   6659072)
    //   rowptr : [6659072,   7059076) -> region to 7059088
    //   packed : [7059088,  13459088)   u32[NE]
    //   wbs/Wt : [13459088, 13524624)   (32 KB used big path; 64 KB fallback Wt)
    //   esrc   : [13524624, 19924624)
    //   yb8    : [19924624, 32724624)
    char* ws = (char*)d_ws;
    unsigned* part   = (unsigned*)ws;
    unsigned* off    = (unsigned*)(ws + 3128000);
    unsigned* sb     = (unsigned*)(ws + 6256000);
    float*    dinv   = (float*)(ws + 6259072);
    int*      rowptr = (int*)(ws + 6659072);
    unsigned* packed = (unsigned*)(ws + 7059088);
    unsigned short* wbs = (unsigned short*)(ws + 13459088);
    float*    Wt     = (float*)(ws + 13459088);
    int*      esrc   = (int*)(ws + 13524624);
    unsigned char* yb8 = (unsigned char*)(ws + 19924624);

    bool big_ws = ws_size >= 32800000;

    if (big_ws) {
        k_hist<<<NB_AC, 256, 0, stream>>>(col, part);
        k_bsum<<<NB_SCAN, 1024, 0, stream>>>(part, sb);
        k_scanpart<<<NB_SCAN, 1024, 0, stream>>>(part, sb, off);
        k_scatter_pk<<<NB_AC, 256, 0, stream>>>(row, col, off, packed);
        k_bucket_csr<<<NBUK, 256, 0, stream>>>(off, packed, dinv, rowptr, esrc);
        k_wb<<<8, 256, 0, stream>>>(W, wbs);
        k_ygemm<<<(NN + 63) / 64, 256, 0, stream>>>(x, wbs, dinv, yb8);
        k_gather_fp8<<<(NN + 7) / 8, 256, 0, stream>>>(rowptr, esrc, yb8, x, dinv, b, out);
    } else {
        int* cnt  = (int*)ws;                 // reuse part region
        int* bsum = (int*)(ws + 6256000);     // 98 ints fit in sb region
        int* boff = (int*)(ws + 400000);      // inside part region, after cnt
        hipMemsetAsync(cnt, 0, NN * sizeof(int), stream);
        k_count<<<(NE + 255) / 256, 256, 0, stream>>>(col, cnt);
        k_blocksum_dinv<<<NBLK, 1024, 0, stream>>>(cnt, bsum, dinv);
        k_scanbsum<<<1, 128, 0, stream>>>(bsum, boff);
        k_scanwrite<<<NBLK, 1024, 0, stream>>>(cnt, boff, rowptr);
        hipMemsetAsync(cnt, 0, NN * sizeof(int), stream);
        k_fill<<<(NE + 255) / 256, 256, 0, stream>>>(row, col, rowptr, cnt, esrc);
        k_gather<<<(NN + 7) / 8, 256, 0, stream>>>(rowptr, esrc, x, dinv, out);
        k_transpose_w<<<DD, DD, 0, stream>>>(W, Wt);
        k_gemm<<<(NN + 63) / 64, 256, 0, stream>>>(x, Wt, b, out);
    }
}

// Round 14
// 124.403 us; speedup vs baseline: 1.4620x; 1.1705x over previous
//
#include <hip/hip_runtime.h>

#define NN 100000
#define NE 1600000
#define DD 128
#define NBLK 98    // ceil(NN / 1024) (fallback scan)
#define NBUK 782   // ceil(NN / 128) buckets of 128 nodes
#define NB_AC 256  // blocks in hist/scatter passes
#define CHUNK 6250 // NE / NB_AC exactly
#define SCAN_N (NBUK * NB_AC)  // 200192
#define NB_SCAN 196            // ceil(SCAN_N / 1024)

typedef __attribute__((ext_vector_type(8))) short bf16x8;
typedef __attribute__((ext_vector_type(4))) float f32x4;
typedef __attribute__((ext_vector_type(2))) float f32x2;

__device__ __forceinline__ float bf2f(unsigned short u) {
    return __uint_as_float(((unsigned)u) << 16);
}
__device__ __forceinline__ unsigned short f2bf(float f) {
    unsigned u = __float_as_uint(f);
    u += 0x7FFFu + ((u >> 16) & 1u);  // round to nearest even
    return (unsigned short)(u >> 16);
}

// ---------------- A: per-block bucket histogram (1024 thr, LDS atomics) ------
__global__ __launch_bounds__(1024) void k_hist(const int* __restrict__ col,
                                               unsigned* __restrict__ part) {
    __shared__ unsigned hist[NBUK];
    int t = threadIdx.x, blk = blockIdx.x;
    for (int i = t; i < NBUK; i += 1024) hist[i] = 0;
    __syncthreads();
    int beg = blk * CHUNK, end = beg + CHUNK;
    for (int e = beg + t; e < end; e += 1024)
        atomicAdd(&hist[col[e] >> 7], 1u);
    __syncthreads();
    for (int i = t; i < NBUK; i += 1024)
        part[(size_t)i * NB_AC + blk] = hist[i];  // bucket-major layout
}

// ---------------- B1: block sums of part (scan order) ----------------
__global__ __launch_bounds__(1024) void k_bsum(const unsigned* __restrict__ part,
                                               unsigned* __restrict__ sb) {
    __shared__ unsigned red[1024];
    int t = threadIdx.x;
    int i = blockIdx.x * 1024 + t;
    red[t] = i < SCAN_N ? part[i] : 0;
    __syncthreads();
    for (int off = 512; off > 0; off >>= 1) {
        if (t < off) red[t] += red[t + off];
        __syncthreads();
    }
    if (t == 0) sb[blockIdx.x] = red[0];
}

// ---------------- B2: exclusive scan part -> off ----------------
__global__ __launch_bounds__(1024) void k_scanpart(const unsigned* __restrict__ part,
                                                   const unsigned* __restrict__ sb,
                                                   unsigned* __restrict__ off) {
    __shared__ unsigned s2[256];
    __shared__ unsigned s[1024];
    int t = threadIdx.x;
    if (t < 256) s2[t] = (t < NB_SCAN) ? sb[t] : 0;
    __syncthreads();
    for (int o = 1; o < 256; o <<= 1) {
        unsigned v = 0;
        if (t < 256 && t >= o) v = s2[t - o];
        __syncthreads();
        if (t < 256) s2[t] += v;
        __syncthreads();
    }
    unsigned boff = blockIdx.x == 0 ? 0 : s2[blockIdx.x - 1];
    int i = blockIdx.x * 1024 + t;
    unsigned v = i < SCAN_N ? part[i] : 0;
    s[t] = v;
    __syncthreads();
    for (int o = 1; o < 1024; o <<= 1) {
        unsigned u = t >= o ? s[t - o] : 0;
        __syncthreads();
        s[t] += u;
        __syncthreads();
    }
    if (i < SCAN_N) off[i] = boff + s[t] - v;  // exclusive prefix
}

// ---------------- C: scatter packed edges (1024 thr) ----------------
__global__ __launch_bounds__(1024) void k_scatter_pk(const int* __restrict__ row,
                                                     const int* __restrict__ col,
                                                     const unsigned* __restrict__ off,
                                                     unsigned* __restrict__ packed) {
    __shared__ unsigned cur[NBUK];
    int t = threadIdx.x, blk = blockIdx.x;
    for (int i = t; i < NBUK; i += 1024) cur[i] = off[(size_t)i * NB_AC + blk];
    __syncthreads();
    int beg = blk * CHUNK, end = beg + CHUNK;
    for (int e = beg + t; e < end; e += 1024) {
        int c = col[e];
        unsigned pos = atomicAdd(&cur[c >> 7], 1u);  // LDS cursor
        packed[pos] = ((unsigned)(c & 127) << 17) | (unsigned)row[e];
    }
}

// ---------------- D: per-bucket CSR finalize: deg/dinv/rowptr/esrc ----------
__global__ __launch_bounds__(256) void k_bucket_csr(const unsigned* __restrict__ off,
                                                    const unsigned* __restrict__ packed,
                                                    float* __restrict__ dinv,
                                                    int* __restrict__ rowptr,
                                                    int* __restrict__ esrc) {
    __shared__ unsigned deg[128], pre[128], tmp[128];
    int t = threadIdx.x;
    int buk = blockIdx.x;
    unsigned bstart = off[(size_t)buk * NB_AC];
    unsigned bend = (buk == NBUK - 1) ? (unsigned)NE : off[(size_t)(buk + 1) * NB_AC];
    if (t < 128) deg[t] = 0;
    __syncthreads();
    for (unsigned e = bstart + t; e < bend; e += 256)
        atomicAdd(&deg[packed[e] >> 17], 1u);
    __syncthreads();
    if (t < 128) tmp[t] = deg[t];
    __syncthreads();
    for (int o = 1; o < 128; o <<= 1) {
        unsigned v = 0;
        if (t < 128 && t >= o) v = tmp[t - o];
        __syncthreads();
        if (t < 128) tmp[t] += v;
        __syncthreads();
    }
    if (t < 128) {
        pre[t] = tmp[t] - deg[t];  // exclusive
        int n = buk * 128 + t;
        if (n < NN) {
            dinv[n] = 1.0f / sqrtf((float)(deg[t] + 1));
            rowptr[n] = (int)(bstart + pre[t]);
        }
    }
    if (buk == NBUK - 1 && t == 0) rowptr[NN] = NE;
    __syncthreads();
    if (t < 128) deg[t] = pre[t];  // reuse as cursor
    __syncthreads();
    for (unsigned e = bstart + t; e < bend; e += 256) {
        unsigned p = packed[e];
        unsigned pos = atomicAdd(&deg[p >> 17], 1u);
        esrc[bstart + pos] = (int)(p & 0x1FFFFu);
    }
}

// ---------------- W -> pre-swizzled bf16 (global, 32 KB) ----------------
__global__ void k_wb(const float* __restrict__ W, unsigned short* __restrict__ wbs) {
    int unit = blockIdx.x * 256 + threadIdx.x;  // 2048 units x 8 elems
    int row = unit >> 4;                        // output-feature row
    int c0 = (unit & 15) * 8;                   // k offset
    float4 v0 = *(const float4*)(W + row * DD + c0);
    float4 v1 = *(const float4*)(W + row * DD + c0 + 4);
    bf16x8 h;
    h[0] = (short)f2bf(v0.x); h[1] = (short)f2bf(v0.y);
    h[2] = (short)f2bf(v0.z); h[3] = (short)f2bf(v0.w);
    h[4] = (short)f2bf(v1.x); h[5] = (short)f2bf(v1.y);
    h[6] = (short)f2bf(v1.z); h[7] = (short)f2bf(v1.w);
    int byte = (row * 256 + c0 * 2) ^ ((row & 7) << 4);  // XOR-swizzle
    *(bf16x8*)((char*)wbs + byte) = h;
}

// ---------------- MFMA GEMM: yb8[m] = fp8( dinv[m] * (x[m] @ W^T) ), permuted ----
// Byte p of row m holds feature n = (p&7)*16 + (p>>3)  (writer-natural order).
__global__ __launch_bounds__(256) void k_ygemm(const float* __restrict__ x,
                                               const unsigned short* __restrict__ wbs,
                                               const float* __restrict__ dinv,
                                               unsigned char* __restrict__ yb8) {
    __shared__ unsigned short wb[DD * DD];  // 32 KB, already swizzled
    int t = threadIdx.x;
#pragma unroll
    for (int i = 0; i < 8; ++i)
        ((float4*)wb)[t + 256 * i] = ((const float4*)wbs)[t + 256 * i];
    __syncthreads();

    int wave = t >> 6;
    int lane = t & 63;
    int lrow = lane & 15;   // A row within 16-tile / D col (feature n)
    int kg = lane >> 4;     // k-group 0..3

    int arow = blockIdx.x * 64 + wave * 16 + lrow;
    int arc = arow < NN ? arow : NN - 1;  // clamped rows' outputs never written
    bf16x8 afrag[4];
#pragma unroll
    for (int ks = 0; ks < 4; ++ks) {
        const float* src = x + (size_t)arc * DD + ks * 32 + kg * 8;
        float4 v0 = *(const float4*)src;
        float4 v1 = *(const float4*)(src + 4);
        bf16x8 h;
        h[0] = (short)f2bf(v0.x); h[1] = (short)f2bf(v0.y);
        h[2] = (short)f2bf(v0.z); h[3] = (short)f2bf(v0.w);
        h[4] = (short)f2bf(v1.x); h[5] = (short)f2bf(v1.y);
        h[6] = (short)f2bf(v1.z); h[7] = (short)f2bf(v1.w);
        afrag[ks] = h;
    }

    f32x4 acc[8];
#pragma unroll
    for (int ct = 0; ct < 8; ++ct) acc[ct] = (f32x4)(0.f);

#pragma unroll
    for (int ct = 0; ct < 8; ++ct) {
        int wrow = ct * 16 + lrow;  // output-feature index
#pragma unroll
        for (int ks = 0; ks < 4; ++ks) {
            int byte = (wrow * 256 + ks * 64 + kg * 16) ^ ((wrow & 7) << 4);
            bf16x8 bfrag = *(const bf16x8*)((char*)wb + byte);
            acc[ct] = __builtin_amdgcn_mfma_f32_16x16x32_bf16(afrag[ks], bfrag, acc[ct], 0, 0, 0);
        }
    }

    // epilogue: pack the 8 ct-values as 8 consecutive fp8 bytes at offset lrow*8.
#pragma unroll
    for (int j = 0; j < 4; ++j) {
        int m = blockIdx.x * 64 + wave * 16 + kg * 4 + j;
        if (m < NN) {
            float s = dinv[m];
            unsigned w0 = 0, w1 = 0;
            w0 = __builtin_amdgcn_cvt_pk_fp8_f32(s * acc[0][j], s * acc[1][j], w0, false);
            w0 = __builtin_amdgcn_cvt_pk_fp8_f32(s * acc[2][j], s * acc[3][j], w0, true);
            w1 = __builtin_amdgcn_cvt_pk_fp8_f32(s * acc[4][j], s * acc[5][j], w1, false);
            w1 = __builtin_amdgcn_cvt_pk_fp8_f32(s * acc[6][j], s * acc[7][j], w1, true);
            uint2 o; o.x = w0; o.y = w1;
            *(uint2*)(yb8 + (size_t)m * DD + lrow * 8) = o;
        }
    }
}

// ---------------- fused gather (fp8) + epilogue (single pass, R9-proven) -----
__global__ __launch_bounds__(256) void k_gather_fp8(const int* __restrict__ rowptr,
                                                    const int* __restrict__ esrc,
                                                    const unsigned char* __restrict__ yb8,
                                                    const float* __restrict__ x,
                                                    const float* __restrict__ dinv,
                                                    const float* __restrict__ bias,
                                                    float* __restrict__ out) {
    int t = threadIdx.x;
    int gl = t & 31;
    int node = blockIdx.x * 8 + (t >> 5);
    if (node >= NN) return;
    int beg = rowptr[node];
    int end = rowptr[node + 1];
    float dc = dinv[node];

    // self term
    unsigned su = *(const unsigned*)(yb8 + (size_t)node * DD + gl * 4);
    f32x2 a01 = __builtin_amdgcn_cvt_pk_f32_fp8(su, false);
    f32x2 a23 = __builtin_amdgcn_cvt_pk_f32_fp8(su, true);

    int e = beg;
    for (; e + 7 < end; e += 8) {
        unsigned uu[8];
#pragma unroll
        for (int u = 0; u < 8; ++u) {
            int r = esrc[e + u];
            uu[u] = *(const unsigned*)(yb8 + (size_t)r * DD + gl * 4);
        }
#pragma unroll
        for (int u = 0; u < 8; ++u) {
            a01 += __builtin_amdgcn_cvt_pk_f32_fp8(uu[u], false);
            a23 += __builtin_amdgcn_cvt_pk_f32_fp8(uu[u], true);
        }
    }
    for (; e < end; ++e) {
        int r = esrc[e];
        unsigned u = *(const unsigned*)(yb8 + (size_t)r * DD + gl * 4);
        a01 += __builtin_amdgcn_cvt_pk_f32_fp8(u, false);
        a23 += __builtin_amdgcn_cvt_pk_f32_fp8(u, true);
    }

    float vals[4] = {a01.x, a01.y, a23.x, a23.y};
    int q = gl >> 1;          // p>>3 for all 4 positions
    int c0 = (gl & 1) * 4;    // (p&7) base
#pragma unroll
    for (int i = 0; i < 4; ++i) {
        int n = (c0 + i) * 16 + q;
        float h = dc * vals[i] + bias[n];
        out[(size_t)node * DD + n] = x[(size_t)node * DD + n] + fmaxf(h, 0.f);
    }
}

// ================= fallback path (small ws) =================
__global__ void k_count(const int* __restrict__ col, int* __restrict__ deg) {
    int i = blockIdx.x * blockDim.x + threadIdx.x;
    if (i < NE) atomicAdd(&deg[col[i]], 1);
}
__global__ __launch_bounds__(1024) void k_blocksum_dinv(const int* __restrict__ deg,
                                                        int* __restrict__ bsum,
                                                        float* __restrict__ dinv) {
    __shared__ int red[1024];
    int t = threadIdx.x;
    int i = blockIdx.x * 1024 + t;
    int d = i < NN ? deg[i] : 0;
    if (i < NN) dinv[i] = 1.0f / sqrtf((float)(d + 1));
    red[t] = d;
    __syncthreads();
    for (int off = 512; off > 0; off >>= 1) {
        if (t < off) red[t] += red[t + off];
        __syncthreads();
    }
    if (t == 0) bsum[blockIdx.x] = red[0];
}
__global__ void k_scanbsum(const int* __restrict__ bsum, int* __restrict__ boff) {
    __shared__ int s[128];
    int t = threadIdx.x;
    s[t] = t < NBLK ? bsum[t] : 0;
    __syncthreads();
    for (int off = 1; off < 128; off <<= 1) {
        int v = t >= off ? s[t - off] : 0;
        __syncthreads();
        s[t] += v;
        __syncthreads();
    }
    if (t < NBLK) boff[t] = (t == 0) ? 0 : s[t - 1];
}
__global__ __launch_bounds__(1024) void k_scanwrite(const int* __restrict__ deg,
                                                    const int* __restrict__ boff,
                                                    int* __restrict__ rowptr) {
    __shared__ int s[1024];
    int t = threadIdx.x;
    int i = blockIdx.x * 1024 + t;
    int v = i < NN ? deg[i] : 0;
    s[t] = v;
    __syncthreads();
    for (int off = 1; off < 1024; off <<= 1) {
        int u = t >= off ? s[t - off] : 0;
        __syncthreads();
        s[t] += u;
        __syncthreads();
    }
    if (i < NN) rowptr[i] = boff[blockIdx.x] + s[t] - v;
    if (i == 0) rowptr[NN] = NE;
}
__global__ void k_fill(const int* __restrict__ row, const int* __restrict__ col,
                       const int* __restrict__ rowptr, int* __restrict__ cnt,
                       int* __restrict__ esrc) {
    int i = blockIdx.x * blockDim.x + threadIdx.x;
    if (i < NE) {
        int c = col[i];
        int pos = rowptr[c] + atomicAdd(&cnt[c], 1);
        esrc[pos] = row[i];
    }
}
__global__ __launch_bounds__(256) void k_gather(const int* __restrict__ rowptr,
                                                const int* __restrict__ esrc,
                                                const float* __restrict__ x,
                                                const float* __restrict__ dinv,
                                                float* __restrict__ agg) {
    int t = threadIdx.x;
    int lane = t & 31;
    int node = blockIdx.x * 8 + (t >> 5);
    if (node >= NN) return;
    int beg = rowptr[node];
    int end = rowptr[node + 1];
    float dc = dinv[node];
    float4 xv = ((const float4*)(x + (size_t)node * DD))[lane];
    float4 acc;
    acc.x = dc * xv.x; acc.y = dc * xv.y; acc.z = dc * xv.z; acc.w = dc * xv.w;
    int e = beg;
    for (; e + 1 < end; e += 2) {
        int r0 = esrc[e];
        int r1 = esrc[e + 1];
        float s0 = dinv[r0];
        float s1 = dinv[r1];
        float4 v0 = ((const float4*)(x + (size_t)r0 * DD))[lane];
        float4 v1 = ((const float4*)(x + (size_t)r1 * DD))[lane];
        acc.x += s0 * v0.x + s1 * v1.x;
        acc.y += s0 * v0.y + s1 * v1.y;
        acc.z += s0 * v0.z + s1 * v1.z;
        acc.w += s0 * v0.w + s1 * v1.w;
    }
    if (e < end) {
        int r = esrc[e];
        float s = dinv[r];
        float4 v = ((const float4*)(x + (size_t)r * DD))[lane];
        acc.x += s * v.x; acc.y += s * v.y; acc.z += s * v.z; acc.w += s * v.w;
    }
    acc.x *= dc; acc.y *= dc; acc.z *= dc; acc.w *= dc;
    ((float4*)(agg + (size_t)node * DD))[lane] = acc;
}
__global__ void k_transpose_w(const float* __restrict__ W, float* __restrict__ Wt) {
    int c = blockIdx.x;
    int k = threadIdx.x;
    Wt[k * DD + c] = W[c * DD + k];
}
__global__ __launch_bounds__(256) void k_gemm(const float* __restrict__ x,
                                              const float* __restrict__ Wt,
                                              const float* __restrict__ bias,
                                              float* __restrict__ out) {
    __shared__ float wt[DD * DD];
    int t = threadIdx.x;
    for (int i = t; i < DD * DD / 4; i += 256)
        ((float4*)wt)[i] = ((const float4*)Wt)[i];
    __syncthreads();

    int grp = t >> 5;
    int c4  = (t & 31) * 4;
    int rbase = blockIdx.x * 64 + grp * 8;

    float acc[8][4];
#pragma unroll
    for (int i = 0; i < 8; i++)
#pragma unroll
        for (int j = 0; j < 4; j++) acc[i][j] = 0.0f;

    for (int k = 0; k < DD; k += 4) {
        float4 w0 = *(const float4*)&wt[(k + 0) * DD + c4];
        float4 w1 = *(const float4*)&wt[(k + 1) * DD + c4];
        float4 w2 = *(const float4*)&wt[(k + 2) * DD + c4];
        float4 w3 = *(const float4*)&wt[(k + 3) * DD + c4];
#pragma unroll
        for (int i = 0; i < 8; i++) {
            int rr = rbase + i;
            rr = rr < NN ? rr : NN - 1;
            float4 a = *(const float4*)&out[(size_t)rr * DD + k];
            acc[i][0] += a.x * w0.x + a.y * w1.x + a.z * w2.x + a.w * w3.x;
            acc[i][1] += a.x * w0.y + a.y * w1.y + a.z * w2.y + a.w * w3.y;
            acc[i][2] += a.x * w0.z + a.y * w1.z + a.z * w2.z + a.w * w3.z;
            acc[i][3] += a.x * w0.w + a.y * w1.w + a.z * w2.w + a.w * w3.w;
        }
    }

    float4 bv = *(const float4*)&bias[c4];
#pragma unroll
    for (int i = 0; i < 8; i++) {
        int r = rbase + i;
        if (r < NN) {
            float4 xv = *(const float4*)&x[(size_t)r * DD + c4];
            float4 o;
            o.x = xv.x + fmaxf(acc[i][0] + bv.x, 0.0f);
            o.y = xv.y + fmaxf(acc[i][1] + bv.y, 0.0f);
            o.z = xv.z + fmaxf(acc[i][2] + bv.z, 0.0f);
            o.w = xv.w + fmaxf(acc[i][3] + bv.w, 0.0f);
            *(float4*)&out[(size_t)r * DD + c4] = o;
        }
    }
}

extern "C" void kernel_launch(void* const* d_in, const int* in_sizes, int n_in,
                              void* d_out, int out_size, void* d_ws, size_t ws_size,
                              hipStream_t stream) {
    const float* x   = (const float*)d_in[0];
    const int*   ei  = (const int*)d_in[1];
    const float* W   = (const float*)d_in[2];
    const float* b   = (const float*)d_in[3];
    const int* row = ei;        // edge_index[0] = source
    const int* col = ei + NE;   // edge_index[1] = target

    float* out = (float*)d_out;

    // workspace layout (bytes), 16-B aligned:
    //   part   : [0,         800768)   u32[SCAN_N]
    //   off    : [800768,   1601536)   u32[SCAN_N]
    //   sb     : [1601536,  1602352)   u32[196] (+pad)
    //   dinv   : [1602352,  2002352)
    //   rowptr : [2002352,  2402356) -> region to 2402368
    //   packed : [2402368,  8802368)   u32[NE]
    //   wbs/Wt : [8802368,  8867904)
    //   esrc   : [8867904, 15267904)
    //   yb8    : [15267904, 28067904)
    char* ws = (char*)d_ws;
    unsigned* part   = (unsigned*)ws;
    unsigned* off    = (unsigned*)(ws + 800768);
    unsigned* sb     = (unsigned*)(ws + 1601536);
    float*    dinv   = (float*)(ws + 1602352);
    int*      rowptr = (int*)(ws + 2002352);
    unsigned* packed = (unsigned*)(ws + 2402368);
    unsigned short* wbs = (unsigned short*)(ws + 8802368);
    float*    Wt     = (float*)(ws + 8802368);
    int*      esrc   = (int*)(ws + 8867904);
    unsigned char* yb8 = (unsigned char*)(ws + 15267904);

    bool big_ws = ws_size >= 28100000;

    if (big_ws) {
        k_hist<<<NB_AC, 1024, 0, stream>>>(col, part);
        k_bsum<<<NB_SCAN, 1024, 0, stream>>>(part, sb);
        k_scanpart<<<NB_SCAN, 1024, 0, stream>>>(part, sb, off);
        k_scatter_pk<<<NB_AC, 1024, 0, stream>>>(row, col, off, packed);
        k_bucket_csr<<<NBUK, 256, 0, stream>>>(off, packed, dinv, rowptr, esrc);
        k_wb<<<8, 256, 0, stream>>>(W, wbs);
        k_ygemm<<<(NN + 63) / 64, 256, 0, stream>>>(x, wbs, dinv, yb8);
        k_gather_fp8<<<(NN + 7) / 8, 256, 0, stream>>>(rowptr, esrc, yb8, x, dinv, b, out);
    } else {
        int* cnt  = (int*)ws;                 // reuse part region
        int* bsum = (int*)(ws + 1601536);     // 98 ints fit in sb region
        int* boff = (int*)(ws + 400000);      // inside part region, after cnt
        hipMemsetAsync(cnt, 0, NN * sizeof(int), stream);
        k_count<<<(NE + 255) / 256, 256, 0, stream>>>(col, cnt);
        k_blocksum_dinv<<<NBLK, 1024, 0, stream>>>(cnt, bsum, dinv);
        k_scanbsum<<<1, 128, 0, stream>>>(bsum, boff);
        k_scanwrite<<<NBLK, 1024, 0, stream>>>(cnt, boff, rowptr);
        hipMemsetAsync(cnt, 0, NN * sizeof(int), stream);
        k_fill<<<(NE + 255) / 256, 256, 0, stream>>>(row, col, rowptr, cnt, esrc);
        k_gather<<<(NN + 7) / 8, 256, 0, stream>>>(rowptr, esrc, x, dinv, out);
        k_transpose_w<<<DD, DD, 0, stream>>>(W, Wt);
        k_gemm<<<(NN + 63) / 64, 256, 0, stream>>>(x, Wt, b, out);
    }
}

// Round 15
// 120.045 us; speedup vs baseline: 1.5151x; 1.0363x over previous
//
#include <hip/hip_runtime.h>

#define NN 100000
#define NE 1600000
#define DD 128
#define NBLK 98    // ceil(NN / 1024) (fallback scan)
#define NBUK 782   // ceil(NN / 128) buckets of 128 nodes
#define NB_AC 256  // blocks in hist/scatter passes
#define CHUNK 6250 // NE / NB_AC exactly
#define SCAN_N (NBUK * NB_AC)  // 200192
#define NB_SCAN 196            // ceil(SCAN_N / 1024)
#define NB_YG ((NN + 63) / 64) // 1563 ygemm blocks

typedef __attribute__((ext_vector_type(8))) short bf16x8;
typedef __attribute__((ext_vector_type(4))) float f32x4;
typedef __attribute__((ext_vector_type(2))) float f32x2;

__device__ __forceinline__ float bf2f(unsigned short u) {
    return __uint_as_float(((unsigned)u) << 16);
}
__device__ __forceinline__ unsigned short f2bf(float f) {
    unsigned u = __float_as_uint(f);
    u += 0x7FFFu + ((u >> 16) & 1u);  // round to nearest even
    return (unsigned short)(u >> 16);
}

// ---------------- A: per-block bucket histogram (1024 thr, LDS atomics) ------
__global__ __launch_bounds__(1024) void k_hist(const int* __restrict__ col,
                                               unsigned* __restrict__ part) {
    __shared__ unsigned hist[NBUK];
    int t = threadIdx.x, blk = blockIdx.x;
    for (int i = t; i < NBUK; i += 1024) hist[i] = 0;
    __syncthreads();
    int beg = blk * CHUNK, end = beg + CHUNK;
    for (int e = beg + t; e < end; e += 1024)
        atomicAdd(&hist[col[e] >> 7], 1u);
    __syncthreads();
    for (int i = t; i < NBUK; i += 1024)
        part[(size_t)i * NB_AC + blk] = hist[i];  // bucket-major layout
}

// ---------------- B1: block sums of part (scan order) ----------------
__global__ __launch_bounds__(1024) void k_bsum(const unsigned* __restrict__ part,
                                               unsigned* __restrict__ sb) {
    __shared__ unsigned red[1024];
    int t = threadIdx.x;
    int i = blockIdx.x * 1024 + t;
    red[t] = i < SCAN_N ? part[i] : 0;
    __syncthreads();
    for (int off = 512; off > 0; off >>= 1) {
        if (t < off) red[t] += red[t + off];
        __syncthreads();
    }
    if (t == 0) sb[blockIdx.x] = red[0];
}

// ---------------- B2: exclusive scan part -> off ----------------
__global__ __launch_bounds__(1024) void k_scanpart(const unsigned* __restrict__ part,
                                                   const unsigned* __restrict__ sb,
                                                   unsigned* __restrict__ off) {
    __shared__ unsigned s2[256];
    __shared__ unsigned s[1024];
    int t = threadIdx.x;
    if (t < 256) s2[t] = (t < NB_SCAN) ? sb[t] : 0;
    __syncthreads();
    for (int o = 1; o < 256; o <<= 1) {
        unsigned v = 0;
        if (t < 256 && t >= o) v = s2[t - o];
        __syncthreads();
        if (t < 256) s2[t] += v;
        __syncthreads();
    }
    unsigned boff = blockIdx.x == 0 ? 0 : s2[blockIdx.x - 1];
    int i = blockIdx.x * 1024 + t;
    unsigned v = i < SCAN_N ? part[i] : 0;
    s[t] = v;
    __syncthreads();
    for (int o = 1; o < 1024; o <<= 1) {
        unsigned u = t >= o ? s[t - o] : 0;
        __syncthreads();
        s[t] += u;
        __syncthreads();
    }
    if (i < SCAN_N) off[i] = boff + s[t] - v;  // exclusive prefix
}

// ---------------- C: scatter packed edges (1024 thr) ----------------
__global__ __launch_bounds__(1024) void k_scatter_pk(const int* __restrict__ row,
                                                     const int* __restrict__ col,
                                                     const unsigned* __restrict__ off,
                                                     unsigned* __restrict__ packed) {
    __shared__ unsigned cur[NBUK];
    int t = threadIdx.x, blk = blockIdx.x;
    for (int i = t; i < NBUK; i += 1024) cur[i] = off[(size_t)i * NB_AC + blk];
    __syncthreads();
    int beg = blk * CHUNK, end = beg + CHUNK;
    for (int e = beg + t; e < end; e += 1024) {
        int c = col[e];
        unsigned pos = atomicAdd(&cur[c >> 7], 1u);  // LDS cursor
        packed[pos] = ((unsigned)(c & 127) << 17) | (unsigned)row[e];
    }
}

// ---------------- D: MERGED finalize ----------------
// Blocks [0, NBUK): per-bucket CSR (deg/dinv/rowptr/esrc).
// Blocks [NBUK, NBUK+NB_YG): MFMA GEMM yb8[m] = fp8(x[m] @ W^T), UNSCALED,
//   permuted layout: byte p of row m holds feature n = (p&7)*16 + (p>>3).
// Independent outputs; uniform per-block branch.
__global__ __launch_bounds__(256) void k_finalize(const unsigned* __restrict__ off,
                                                  const unsigned* __restrict__ packed,
                                                  float* __restrict__ dinv,
                                                  int* __restrict__ rowptr,
                                                  int* __restrict__ esrc,
                                                  const float* __restrict__ x,
                                                  const float* __restrict__ W,
                                                  unsigned char* __restrict__ yb8) {
    __shared__ unsigned short wb[DD * DD];  // 32 KB (ygemm branch)
    __shared__ unsigned deg[128], pre[128], tmp[128];
    int t = threadIdx.x;

    if (blockIdx.x < NBUK) {
        // ---- bucket CSR ----
        int buk = blockIdx.x;
        unsigned bstart = off[(size_t)buk * NB_AC];
        unsigned bend = (buk == NBUK - 1) ? (unsigned)NE : off[(size_t)(buk + 1) * NB_AC];
        if (t < 128) deg[t] = 0;
        __syncthreads();
        for (unsigned e = bstart + t; e < bend; e += 256)
            atomicAdd(&deg[packed[e] >> 17], 1u);
        __syncthreads();
        if (t < 128) tmp[t] = deg[t];
        __syncthreads();
        for (int o = 1; o < 128; o <<= 1) {
            unsigned v = 0;
            if (t < 128 && t >= o) v = tmp[t - o];
            __syncthreads();
            if (t < 128) tmp[t] += v;
            __syncthreads();
        }
        if (t < 128) {
            pre[t] = tmp[t] - deg[t];  // exclusive
            int n = buk * 128 + t;
            if (n < NN) {
                dinv[n] = 1.0f / sqrtf((float)(deg[t] + 1));
                rowptr[n] = (int)(bstart + pre[t]);
            }
        }
        if (buk == NBUK - 1 && t == 0) rowptr[NN] = NE;
        __syncthreads();
        if (t < 128) deg[t] = pre[t];  // reuse as cursor
        __syncthreads();
        for (unsigned e = bstart + t; e < bend; e += 256) {
            unsigned p = packed[e];
            unsigned pos = atomicAdd(&deg[p >> 17], 1u);
            esrc[bstart + pos] = (int)(p & 0x1FFFFu);
        }
    } else {
        // ---- ygemm ----
        int blk = blockIdx.x - NBUK;
        // stage W -> wb (f32 -> bf16), XOR-swizzled
#pragma unroll
        for (int it = 0; it < 8; ++it) {
            int unit = t + 256 * it;       // 2048 units x 8 elems
            int wrow = unit >> 4;
            int c0 = (unit & 15) * 8;
            float4 v0 = *(const float4*)(W + wrow * DD + c0);
            float4 v1 = *(const float4*)(W + wrow * DD + c0 + 4);
            bf16x8 h;
            h[0] = (short)f2bf(v0.x); h[1] = (short)f2bf(v0.y);
            h[2] = (short)f2bf(v0.z); h[3] = (short)f2bf(v0.w);
            h[4] = (short)f2bf(v1.x); h[5] = (short)f2bf(v1.y);
            h[6] = (short)f2bf(v1.z); h[7] = (short)f2bf(v1.w);
            int byte = (wrow * 256 + c0 * 2) ^ ((wrow & 7) << 4);
            *(bf16x8*)((char*)wb + byte) = h;
        }
        __syncthreads();

        int wave = t >> 6;
        int lane = t & 63;
        int lrow = lane & 15;
        int kg = lane >> 4;

        int arow = blk * 64 + wave * 16 + lrow;
        int arc = arow < NN ? arow : NN - 1;  // clamped rows never written
        bf16x8 afrag[4];
#pragma unroll
        for (int ks = 0; ks < 4; ++ks) {
            const float* src = x + (size_t)arc * DD + ks * 32 + kg * 8;
            float4 v0 = *(const float4*)src;
            float4 v1 = *(const float4*)(src + 4);
            bf16x8 h;
            h[0] = (short)f2bf(v0.x); h[1] = (short)f2bf(v0.y);
            h[2] = (short)f2bf(v0.z); h[3] = (short)f2bf(v0.w);
            h[4] = (short)f2bf(v1.x); h[5] = (short)f2bf(v1.y);
            h[6] = (short)f2bf(v1.z); h[7] = (short)f2bf(v1.w);
            afrag[ks] = h;
        }

        f32x4 acc[8];
#pragma unroll
        for (int ct = 0; ct < 8; ++ct) acc[ct] = (f32x4)(0.f);

#pragma unroll
        for (int ct = 0; ct < 8; ++ct) {
            int wrow = ct * 16 + lrow;
#pragma unroll
            for (int ks = 0; ks < 4; ++ks) {
                int byte = (wrow * 256 + ks * 64 + kg * 16) ^ ((wrow & 7) << 4);
                bf16x8 bfrag = *(const bf16x8*)((char*)wb + byte);
                acc[ct] = __builtin_amdgcn_mfma_f32_16x16x32_bf16(afrag[ks], bfrag, acc[ct], 0, 0, 0);
            }
        }

#pragma unroll
        for (int j = 0; j < 4; ++j) {
            int m = blk * 64 + wave * 16 + kg * 4 + j;
            if (m < NN) {
                unsigned w0 = 0, w1 = 0;
                w0 = __builtin_amdgcn_cvt_pk_fp8_f32(acc[0][j], acc[1][j], w0, false);
                w0 = __builtin_amdgcn_cvt_pk_fp8_f32(acc[2][j], acc[3][j], w0, true);
                w1 = __builtin_amdgcn_cvt_pk_fp8_f32(acc[4][j], acc[5][j], w1, false);
                w1 = __builtin_amdgcn_cvt_pk_fp8_f32(acc[6][j], acc[7][j], w1, true);
                uint2 o; o.x = w0; o.y = w1;
                *(uint2*)(yb8 + (size_t)m * DD + lrow * 8) = o;
            }
        }
    }
}

// ---------------- fused gather (fp8, per-edge dinv) + epilogue ----------------
// out[c][n] = x[c][n] + relu( dc*( sum_r dinv[r]*y_r[p] + dc*y_c[p] ) + b[n] )
__global__ __launch_bounds__(256) void k_gather_fp8(const int* __restrict__ rowptr,
                                                    const int* __restrict__ esrc,
                                                    const unsigned char* __restrict__ yb8,
                                                    const float* __restrict__ x,
                                                    const float* __restrict__ dinv,
                                                    const float* __restrict__ bias,
                                                    float* __restrict__ out) {
    int t = threadIdx.x;
    int gl = t & 31;
    int node = blockIdx.x * 8 + (t >> 5);
    if (node >= NN) return;
    int beg = rowptr[node];
    int end = rowptr[node + 1];
    float dc = dinv[node];

    // self term: dc * y_c
    unsigned su = *(const unsigned*)(yb8 + (size_t)node * DD + gl * 4);
    f32x2 a01 = dc * __builtin_amdgcn_cvt_pk_f32_fp8(su, false);
    f32x2 a23 = dc * __builtin_amdgcn_cvt_pk_f32_fp8(su, true);

    int e = beg;
    for (; e + 7 < end; e += 8) {
        unsigned uu[8];
        float ss[8];
#pragma unroll
        for (int u = 0; u < 8; ++u) {
            int r = esrc[e + u];
            uu[u] = *(const unsigned*)(yb8 + (size_t)r * DD + gl * 4);
            ss[u] = dinv[r];
        }
#pragma unroll
        for (int u = 0; u < 8; ++u) {
            a01 += ss[u] * __builtin_amdgcn_cvt_pk_f32_fp8(uu[u], false);
            a23 += ss[u] * __builtin_amdgcn_cvt_pk_f32_fp8(uu[u], true);
        }
    }
    for (; e < end; ++e) {
        int r = esrc[e];
        unsigned u = *(const unsigned*)(yb8 + (size_t)r * DD + gl * 4);
        float s = dinv[r];
        a01 += s * __builtin_amdgcn_cvt_pk_f32_fp8(u, false);
        a23 += s * __builtin_amdgcn_cvt_pk_f32_fp8(u, true);
    }

    float vals[4] = {a01.x, a01.y, a23.x, a23.y};
    int q = gl >> 1;          // p>>3 for all 4 positions
    int c0 = (gl & 1) * 4;    // (p&7) base
    const float* xp = x + (size_t)node * DD;
    float* op = out + (size_t)node * DD;
#pragma unroll
    for (int i = 0; i < 4; ++i) {
        int n = (c0 + i) * 16 + q;
        float xv = __builtin_nontemporal_load(xp + n);
        float h = dc * vals[i] + bias[n];
        __builtin_nontemporal_store(xv + fmaxf(h, 0.f), op + n);
    }
}

// ================= fallback path (small ws) =================
__global__ void k_count(const int* __restrict__ col, int* __restrict__ deg) {
    int i = blockIdx.x * blockDim.x + threadIdx.x;
    if (i < NE) atomicAdd(&deg[col[i]], 1);
}
__global__ __launch_bounds__(1024) void k_blocksum_dinv(const int* __restrict__ deg,
                                                        int* __restrict__ bsum,
                                                        float* __restrict__ dinv) {
    __shared__ int red[1024];
    int t = threadIdx.x;
    int i = blockIdx.x * 1024 + t;
    int d = i < NN ? deg[i] : 0;
    if (i < NN) dinv[i] = 1.0f / sqrtf((float)(d + 1));
    red[t] = d;
    __syncthreads();
    for (int off = 512; off > 0; off >>= 1) {
        if (t < off) red[t] += red[t + off];
        __syncthreads();
    }
    if (t == 0) bsum[blockIdx.x] = red[0];
}
__global__ void k_scanbsum(const int* __restrict__ bsum, int* __restrict__ boff) {
    __shared__ int s[128];
    int t = threadIdx.x;
    s[t] = t < NBLK ? bsum[t] : 0;
    __syncthreads();
    for (int off = 1; off < 128; off <<= 1) {
        int v = t >= off ? s[t - off] : 0;
        __syncthreads();
        s[t] += v;
        __syncthreads();
    }
    if (t < NBLK) boff[t] = (t == 0) ? 0 : s[t - 1];
}
__global__ __launch_bounds__(1024) void k_scanwrite(const int* __restrict__ deg,
                                                    const int* __restrict__ boff,
                                                    int* __restrict__ rowptr) {
    __shared__ int s[1024];
    int t = threadIdx.x;
    int i = blockIdx.x * 1024 + t;
    int v = i < NN ? deg[i] : 0;
    s[t] = v;
    __syncthreads();
    for (int off = 1; off < 1024; off <<= 1) {
        int u = t >= off ? s[t - off] : 0;
        __syncthreads();
        s[t] += u;
        __syncthreads();
    }
    if (i < NN) rowptr[i] = boff[blockIdx.x] + s[t] - v;
    if (i == 0) rowptr[NN] = NE;
}
__global__ void k_fill(const int* __restrict__ row, const int* __restrict__ col,
                       const int* __restrict__ rowptr, int* __restrict__ cnt,
                       int* __restrict__ esrc) {
    int i = blockIdx.x * blockDim.x + threadIdx.x;
    if (i < NE) {
        int c = col[i];
        int pos = rowptr[c] + atomicAdd(&cnt[c], 1);
        esrc[pos] = row[i];
    }
}
__global__ __launch_bounds__(256) void k_gather(const int* __restrict__ rowptr,
                                                const int* __restrict__ esrc,
                                                const float* __restrict__ x,
                                                const float* __restrict__ dinv,
                                                float* __restrict__ agg) {
    int t = threadIdx.x;
    int lane = t & 31;
    int node = blockIdx.x * 8 + (t >> 5);
    if (node >= NN) return;
    int beg = rowptr[node];
    int end = rowptr[node + 1];
    float dc = dinv[node];
    float4 xv = ((const float4*)(x + (size_t)node * DD))[lane];
    float4 acc;
    acc.x = dc * xv.x; acc.y = dc * xv.y; acc.z = dc * xv.z; acc.w = dc * xv.w;
    int e = beg;
    for (; e + 1 < end; e += 2) {
        int r0 = esrc[e];
        int r1 = esrc[e + 1];
        float s0 = dinv[r0];
        float s1 = dinv[r1];
        float4 v0 = ((const float4*)(x + (size_t)r0 * DD))[lane];
        float4 v1 = ((const float4*)(x + (size_t)r1 * DD))[lane];
        acc.x += s0 * v0.x + s1 * v1.x;
        acc.y += s0 * v0.y + s1 * v1.y;
        acc.z += s0 * v0.z + s1 * v1.z;
        acc.w += s0 * v0.w + s1 * v1.w;
    }
    if (e < end) {
        int r = esrc[e];
        float s = dinv[r];
        float4 v = ((const float4*)(x + (size_t)r * DD))[lane];
        acc.x += s * v.x; acc.y += s * v.y; acc.z += s * v.z; acc.w += s * v.w;
    }
    acc.x *= dc; acc.y *= dc; acc.z *= dc; acc.w *= dc;
    ((float4*)(agg + (size_t)node * DD))[lane] = acc;
}
__global__ void k_transpose_w(const float* __restrict__ W, float* __restrict__ Wt) {
    int c = blockIdx.x;
    int k = threadIdx.x;
    Wt[k * DD + c] = W[c * DD + k];
}
__global__ __launch_bounds__(256) void k_gemm(const float* __restrict__ x,
                                              const float* __restrict__ Wt,
                                              const float* __restrict__ bias,
                                              float* __restrict__ out) {
    __shared__ float wt[DD * DD];
    int t = threadIdx.x;
    for (int i = t; i < DD * DD / 4; i += 256)
        ((float4*)wt)[i] = ((const float4*)Wt)[i];
    __syncthreads();

    int grp = t >> 5;
    int c4  = (t & 31) * 4;
    int rbase = blockIdx.x * 64 + grp * 8;

    float acc[8][4];
#pragma unroll
    for (int i = 0; i < 8; i++)
#pragma unroll
        for (int j = 0; j < 4; j++) acc[i][j] = 0.0f;

    for (int k = 0; k < DD; k += 4) {
        float4 w0 = *(const float4*)&wt[(k + 0) * DD + c4];
        float4 w1 = *(const float4*)&wt[(k + 1) * DD + c4];
        float4 w2 = *(const float4*)&wt[(k + 2) * DD + c4];
        float4 w3 = *(const float4*)&wt[(k + 3) * DD + c4];
#pragma unroll
        for (int i = 0; i < 8; i++) {
            int rr = rbase + i;
            rr = rr < NN ? rr : NN - 1;
            float4 a = *(const float4*)&out[(size_t)rr * DD + k];
            acc[i][0] += a.x * w0.x + a.y * w1.x + a.z * w2.x + a.w * w3.x;
            acc[i][1] += a.x * w0.y + a.y * w1.y + a.z * w2.y + a.w * w3.y;
            acc[i][2] += a.x * w0.z + a.y * w1.z + a.z * w2.z + a.w * w3.z;
            acc[i][3] += a.x * w0.w + a.y * w1.w + a.z * w2.w + a.w * w3.w;
        }
    }

    float4 bv = *(const float4*)&bias[c4];
#pragma unroll
    for (int i = 0; i < 8; i++) {
        int r = rbase + i;
        if (r < NN) {
            float4 xv = *(const float4*)&x[(size_t)r * DD + c4];
            float4 o;
            o.x = xv.x + fmaxf(acc[i][0] + bv.x, 0.0f);
            o.y = xv.y + fmaxf(acc[i][1] + bv.y, 0.0f);
            o.z = xv.z + fmaxf(acc[i][2] + bv.z, 0.0f);
            o.w = xv.w + fmaxf(acc[i][3] + bv.w, 0.0f);
            *(float4*)&out[(size_t)r * DD + c4] = o;
        }
    }
}

extern "C" void kernel_launch(void* const* d_in, const int* in_sizes, int n_in,
                              void* d_out, int out_size, void* d_ws, size_t ws_size,
                              hipStream_t stream) {
    const float* x   = (const float*)d_in[0];
    const int*   ei  = (const int*)d_in[1];
    const float* W   = (const float*)d_in[2];
    const float* b   = (const float*)d_in[3];
    const int* row = ei;        // edge_index[0] = source
    const int* col = ei + NE;   // edge_index[1] = target

    float* out = (float*)d_out;

    // workspace layout (bytes), 16-B aligned:
    //   part   : [0,         800768)   u32[SCAN_N]
    //   off    : [800768,   1601536)   u32[SCAN_N]
    //   sb     : [1601536,  1602352)   u32[196] (+pad)
    //   dinv   : [1602352,  2002352)
    //   rowptr : [2002352,  2402356) -> region to 2402368
    //   packed : [2402368,  8802368)   u32[NE]
    //   Wt     : [8802368,  8867904)   (fallback only)
    //   esrc   : [8867904, 15267904)
    //   yb8    : [15267904, 28067904)
    char* ws = (char*)d_ws;
    unsigned* part   = (unsigned*)ws;
    unsigned* off    = (unsigned*)(ws + 800768);
    unsigned* sb     = (unsigned*)(ws + 1601536);
    float*    dinv   = (float*)(ws + 1602352);
    int*      rowptr = (int*)(ws + 2002352);
    unsigned* packed = (unsigned*)(ws + 2402368);
    float*    Wt     = (float*)(ws + 8802368);
    int*      esrc   = (int*)(ws + 8867904);
    unsigned char* yb8 = (unsigned char*)(ws + 15267904);

    bool big_ws = ws_size >= 28100000;

    if (big_ws) {
        k_hist<<<NB_AC, 1024, 0, stream>>>(col, part);
        k_bsum<<<NB_SCAN, 1024, 0, stream>>>(part, sb);
        k_scanpart<<<NB_SCAN, 1024, 0, stream>>>(part, sb, off);
        k_scatter_pk<<<NB_AC, 1024, 0, stream>>>(row, col, off, packed);
        k_finalize<<<NBUK + NB_YG, 256, 0, stream>>>(off, packed, dinv, rowptr, esrc, x, W, yb8);
        k_gather_fp8<<<(NN + 7) / 8, 256, 0, stream>>>(rowptr, esrc, yb8, x, dinv, b, out);
    } else {
        int* cnt  = (int*)ws;                 // reuse part region
        int* bsum = (int*)(ws + 1601536);     // 98 ints fit in sb region
        int* boff = (int*)(ws + 400000);      // inside part region, after cnt
        hipMemsetAsync(cnt, 0, NN * sizeof(int), stream);
        k_count<<<(NE + 255) / 256, 256, 0, stream>>>(col, cnt);
        k_blocksum_dinv<<<NBLK, 1024, 0, stream>>>(cnt, bsum, dinv);
        k_scanbsum<<<1, 128, 0, stream>>>(bsum, boff);
        k_scanwrite<<<NBLK, 1024, 0, stream>>>(cnt, boff, rowptr);
        hipMemsetAsync(cnt, 0, NN * sizeof(int), stream);
        k_fill<<<(NE + 255) / 256, 256, 0, stream>>>(row, col, rowptr, cnt, esrc);
        k_gather<<<(NN + 7) / 8, 256, 0, stream>>>(rowptr, esrc, x, dinv, out);
        k_transpose_w<<<DD, DD, 0, stream>>>(W, Wt);
        k_gemm<<<(NN + 63) / 64, 256, 0, stream>>>(x, Wt, b, out);
    }
}